// Round 1
// baseline (820.228 us; speedup 1.0000x reference)
//
#include <hip/hip_runtime.h>

#define B 32
#define L 2048
#define H 1024
#define K2 2048            // 2*H
#define NL 8               // l-values per wave in scores kernel
#define HSPLIT 16
#define HCHUNK (H / HSPLIT)  // 64

// ---------------------------------------------------------------------------
// v[b,h] = sum_g hs[b,g] * attn_W[g,h]        (32 x 1024)
// grid: 128 blocks x 256 thr; each thread one (b,h); b uniform per block.
// ---------------------------------------------------------------------------
__global__ __launch_bounds__(256) void v_kernel(const float* __restrict__ hs,
                                                const float* __restrict__ attn_W,
                                                float* __restrict__ v) {
    int tid = blockIdx.x * 256 + threadIdx.x;   // 0..32767
    int b = tid >> 10;
    int h = tid & (H - 1);
    const float* hsb = hs + b * H;
    float acc = 0.f;
    #pragma unroll 8
    for (int g = 0; g < H; ++g)
        acc = fmaf(hsb[g], attn_W[g * H + h], acc);   // attn_W read coalesced
    v[tid] = acc;
}

// ---------------------------------------------------------------------------
// pw[s][b][k] = sum_{h in chunk s} v[b,h] * reduce_W[h,k]
// grid: (K2/512, HSPLIT) = (4,16) blocks x 256 thr; float2 over k;
// v reads are wave-uniform -> scalar-load path. acc[32] float2 = 64 VGPR.
// ---------------------------------------------------------------------------
__global__ __launch_bounds__(256) void w_partial_kernel(const float* __restrict__ v,
                                                        const float* __restrict__ rW,
                                                        float* __restrict__ pw) {
    int k2 = blockIdx.x * 256 + threadIdx.x;    // float2 column, 0..1023
    int h0 = blockIdx.y * HCHUNK;
    const float2* rW2 = (const float2*)rW;
    float2 acc[B];
    #pragma unroll
    for (int b = 0; b < B; ++b) { acc[b].x = 0.f; acc[b].y = 0.f; }
    for (int h = h0; h < h0 + HCHUNK; ++h) {
        float2 rw = rW2[h * (K2 / 2) + k2];     // coalesced
        #pragma unroll
        for (int b = 0; b < B; ++b) {
            float vb = v[b * H + h];            // uniform -> s_load
            acc[b].x = fmaf(vb, rw.x, acc[b].x);
            acc[b].y = fmaf(vb, rw.y, acc[b].y);
        }
    }
    float2* pw2 = (float2*)pw;
    #pragma unroll
    for (int b = 0; b < B; ++b)
        pw2[(blockIdx.y * B + b) * (K2 / 2) + k2] = acc[b];
}

// w[b,k] = sum_s pw[s][b][k]
__global__ __launch_bounds__(256) void w_reduce_kernel(const float* __restrict__ pw,
                                                       float* __restrict__ w) {
    int i = blockIdx.x * 256 + threadIdx.x;     // 0..65535  (= b*K2 + k)
    float s = 0.f;
    #pragma unroll
    for (int p = 0; p < HSPLIT; ++p) s += pw[p * (B * K2) + i];
    w[i] = s;
}

// ---------------------------------------------------------------------------
// scores[b,l] = w[b,:] . enc[l,b,:]   -- THE streaming kernel (512 MB read)
// One wave handles NL=8 consecutive l for one b: w float4 reused 8x.
// grid: 2048 blocks x 256 thr (4 waves/block), 8192 waves = 32/CU.
// ---------------------------------------------------------------------------
__global__ __launch_bounds__(256) void scores_kernel(const float4* __restrict__ enc,
                                                     const float4* __restrict__ w,
                                                     float* __restrict__ scores) {
    int wid  = blockIdx.x * 4 + (threadIdx.x >> 6);
    int lane = threadIdx.x & 63;
    int b  = wid & (B - 1);
    int l0 = (wid >> 5) * NL;
    const float4* wb = w + b * (K2 / 4);        // 512 float4, L2-resident
    float acc[NL];
    #pragma unroll
    for (int i = 0; i < NL; ++i) acc[i] = 0.f;
    for (int j = 0; j < (K2 / 4) / 64; ++j) {   // 8 iterations
        int idx = j * 64 + lane;
        float4 wv = wb[idx];
        #pragma unroll
        for (int i = 0; i < NL; ++i) {
            float4 e = enc[(size_t)((l0 + i) * B + b) * (K2 / 4) + idx];  // 1KB/wave coalesced
            acc[i] = fmaf(wv.x, e.x, acc[i]);
            acc[i] = fmaf(wv.y, e.y, acc[i]);
            acc[i] = fmaf(wv.z, e.z, acc[i]);
            acc[i] = fmaf(wv.w, e.w, acc[i]);
        }
    }
    #pragma unroll
    for (int i = 0; i < NL; ++i) {
        float s = acc[i];
        #pragma unroll
        for (int off = 32; off > 0; off >>= 1) s += __shfl_down(s, off, 64);
        if (lane == 0) scores[b * L + l0 + i] = s;
    }
}

// ---------------------------------------------------------------------------
// In-place row softmax over l (row length L=2048), one block per b.
// ---------------------------------------------------------------------------
__global__ __launch_bounds__(256) void softmax_kernel(float* __restrict__ out) {
    int b = blockIdx.x;
    int t = threadIdx.x;
    float* row = out + b * L;
    float vals[8];
    float m = -3.4e38f;
    #pragma unroll
    for (int i = 0; i < 8; ++i) { vals[i] = row[t + i * 256]; m = fmaxf(m, vals[i]); }
    __shared__ float wred[4];
    int wv = t >> 6, lane = t & 63;
    #pragma unroll
    for (int off = 1; off < 64; off <<= 1) m = fmaxf(m, __shfl_xor(m, off, 64));
    if (lane == 0) wred[wv] = m;
    __syncthreads();
    m = fmaxf(fmaxf(wred[0], wred[1]), fmaxf(wred[2], wred[3]));
    __syncthreads();                     // wred reused for the sum
    float s = 0.f;
    #pragma unroll
    for (int i = 0; i < 8; ++i) { vals[i] = __expf(vals[i] - m); s += vals[i]; }
    #pragma unroll
    for (int off = 1; off < 64; off <<= 1) s += __shfl_xor(s, off, 64);
    if (lane == 0) wred[wv] = s;
    __syncthreads();
    s = wred[0] + wred[1] + wred[2] + wred[3];
    float inv = 1.f / s;
    #pragma unroll
    for (int i = 0; i < 8; ++i) row[t + i * 256] = vals[i] * inv;
}

extern "C" void kernel_launch(void* const* d_in, const int* in_sizes, int n_in,
                              void* d_out, int out_size, void* d_ws, size_t ws_size,
                              hipStream_t stream) {
    const float* hs  = (const float*)d_in[0];   // (B,H)
    const float* enc = (const float*)d_in[1];   // (L,B,2H)
    const float* rW  = (const float*)d_in[2];   // (H,2H)
    // d_in[3] = reduce_b : cancels in softmax (constant per b)
    const float* aW  = (const float*)d_in[4];   // (H,H)
    // d_in[5] = attn_b  : cancels in softmax (constant per b)
    float* out = (float*)d_out;                 // (B,L) fp32

    char* ws = (char*)d_ws;
    float* v  = (float*)(ws);                           // B*H      = 128 KB
    float* w  = (float*)(ws + 131072);                  // B*K2     = 256 KB
    float* pw = (float*)(ws + 131072 + 262144);         // HSPLIT*B*K2 = 4 MB

    v_kernel<<<(B * H) / 256, 256, 0, stream>>>(hs, aW, v);

    dim3 g2(K2 / 512, HSPLIT);                          // (4,16)
    w_partial_kernel<<<g2, 256, 0, stream>>>(v, rW, pw);
    w_reduce_kernel<<<(B * K2) / 256, 256, 0, stream>>>(pw, w);

    scores_kernel<<<(L / NL) * B / 4, 256, 0, stream>>>((const float4*)enc,
                                                        (const float4*)w, out);
    softmax_kernel<<<B, 256, 0, stream>>>(out);
}